// Round 10
// baseline (298.559 us; speedup 1.0000x reference)
//
#include <hip/hip_runtime.h>
#include <hip/hip_bf16.h>

#define N_ROWS 8192
#define D_DIM  256

// loss_i = log(sum_{j != i} exp(<x_i,y_j>/T)) - <x_i,y_i>/T ; out = mean_i loss_i
// fp8 e4m3 inputs (scale 64); acc = 4096*<x,y>; 1/4096 folded into constants.
// K-dim stored PERMUTED for 64B staging rounds: element k=(2*rh+u)*32+q*8+j is
// stored at k' = rh*64 + q*16 + u*8 + j  (rh=round 0..3, q=quad, u=k-step par).
// -> per lane per round the A/B fragment is 16 contiguous bytes (1 ds_read_b128
//    covering 2 k-steps). Dots are invariant to a shared k-permutation.
static constexpr float kQuantScale = 64.0f;
static constexpr float kScaleAcc = 20.609929155556627f / 4096.0f;  // (1/T)*log2(e)/4096
static constexpr float kInvTAcc  = 14.285714285714286f / 4096.0f;  // (1/T)/4096

typedef float f32x4 __attribute__((ext_vector_type(4)));
typedef long  lx2   __attribute__((ext_vector_type(2)));

// async 16B global->LDS: LDS dest = wave-uniform base + lane*16
__device__ __forceinline__ void gl_lds16(const void* g, void* l) {
  __builtin_amdgcn_global_load_lds(
      (const __attribute__((address_space(1))) void*)g,
      (__attribute__((address_space(3))) void*)l, 16, 0, 0);
}

// ---------------- fp32 -> fp8 e4m3 pre-convert (k-permuted) + ws/out init ------
__global__ __launch_bounds__(256)
void cvt_fp8_kernel(const float* __restrict__ x, const float* __restrict__ y,
                    unsigned char* __restrict__ xq, unsigned char* __restrict__ yq,
                    float* __restrict__ rowsum, float* __restrict__ out) {
  if (blockIdx.x == 0) {
    for (int i = threadIdx.x; i < N_ROWS; i += 256) rowsum[i] = 0.f;
    if (threadIdx.x == 0) out[0] = 0.f;
  }
  const int per_mat = N_ROWS * D_DIM / 8;  // 8 elements per thread
  int idx = blockIdx.x * blockDim.x + threadIdx.x;
  const float* src = x;
  unsigned char* dst = xq;
  int i = idx;
  if (idx >= per_mat) { src = y; dst = yq; i = idx - per_mat; }
  float4 a = ((const float4*)src)[2 * (size_t)i];
  float4 b = ((const float4*)src)[2 * (size_t)i + 1];
  int v0 = 0, v1 = 0;
  v0 = __builtin_amdgcn_cvt_pk_fp8_f32(a.x * kQuantScale, a.y * kQuantScale, v0, false);
  v0 = __builtin_amdgcn_cvt_pk_fp8_f32(a.z * kQuantScale, a.w * kQuantScale, v0, true);
  v1 = __builtin_amdgcn_cvt_pk_fp8_f32(b.x * kQuantScale, b.y * kQuantScale, v1, false);
  v1 = __builtin_amdgcn_cvt_pk_fp8_f32(b.z * kQuantScale, b.w * kQuantScale, v1, true);
  // elements k = c*8..c*8+7, c = (k-step ug)*4 + q; store at rh*64 + q*16 + u*8
  const int row = i >> 5;
  const int c   = i & 31;
  const int ug  = c >> 2;         // k-step 0..7
  const int q   = c & 3;          // quad
  const int rh  = ug >> 1;        // staging round 0..3
  const int u   = ug & 1;         // k-step parity within round
  const size_t off = (size_t)row * D_DIM + rh * 64 + q * 16 + u * 8;
  *(int2*)(dst + off) = make_int2(v0, v1);
}

// ---------------- persistent fused GEMM(fp8) + exp + row-sum -------------------
// 256 persistent blocks (1/CU), 512 threads = 8 waves (2x4). Each block owns
// X-row-block bi = b>>3 (256 rows) and computes 4 tiles bj = (b&7)*4 + tt of
// 256x256. Flat loop over 16 rounds (4 tiles x 4 K-quarters of 64B), LDS
// double-buffered (2 x 32 KB = 64 KB): stage round r+1 after the barrier, then
// ds_read + 64 MFMAs/wave on round r. Wave tile 128x64 = 8x4 MFMA tiles.
// LDS swizzle: row's chunk position p holds global chunk p^((row>>1)&3) ->
// fragment b128 reads hit each 4-bank group exactly 2x (free).
// No device-scope fences (R4 lesson: they nuke per-XCD L2).
__global__ __launch_bounds__(512, 2)
void infonce_gemm(const unsigned char* __restrict__ X,
                  const unsigned char* __restrict__ Y,
                  float* __restrict__ rowsum, float* __restrict__ diag) {
  __shared__ unsigned char Xs[2][256 * 64];   // 2 x 16 KB
  __shared__ unsigned char Ys[2][256 * 64];   // 2 x 16 KB

  const int b  = blockIdx.x;        // 0..255
  const int bi = b >> 3;            // 0..31, fixed X-row-block (256 rows)
  const int gj = b & 7;             // col-group: bj = gj*4 + tt, tt=0..3

  const int t    = threadIdx.x;
  const int lane = t & 63;
  const int wave = t >> 6;        // 0..7
  const int wm   = wave >> 2;     // 0..1  (128-row half)
  const int wn   = wave & 3;      // 0..3  (64-col quarter)
  const int quad = lane >> 4;     // 0..3
  const int l15  = lane & 15;

  const unsigned char* Xblk = X + (size_t)(bi * 256) * D_DIM;

  // staging geometry: 1024 slots(16B) per matrix per round; it in {0,1}
  int sc0[2], srow[2], scg[2];
#pragma unroll
  for (int it = 0; it < 2; ++it) {
    const int c0 = (it * 8 + wave) * 64;   // wave-uniform slot base
    const int s  = c0 + lane;
    const int row = s >> 2;                // 0..255
    sc0[it]  = c0;
    srow[it] = row;
    scg[it]  = (s & 3) ^ ((row >> 1) & 3); // global chunk for this LDS slot
  }

  f32x4 acc[8][4];
#pragma unroll
  for (int a = 0; a < 8; ++a)
#pragma unroll
    for (int c = 0; c < 4; ++c) acc[a][c] = (f32x4){0.f, 0.f, 0.f, 0.f};

  // prologue: stage round 0 (tile 0, quarter 0) into buffer 0
  {
    const unsigned char* Yblk = Y + (size_t)((gj * 4) * 256) * D_DIM;
#pragma unroll
    for (int it = 0; it < 2; ++it) {
      const size_t go = (size_t)srow[it] * D_DIM + scg[it] * 16;
      gl_lds16(Xblk + go, &Xs[0][sc0[it] * 16]);
      gl_lds16(Yblk + go, &Ys[0][sc0[it] * 16]);
    }
  }

#pragma unroll 4
  for (int r = 0; r < 16; ++r) {
    const int tt = r >> 2;        // tile 0..3
    const int rh = r & 3;         // K-quarter
    const int p  = r & 1;         // LDS buffer parity

    __syncthreads();   // staging of round r drained (vmcnt(0) before barrier)

    if (r < 15) {      // stage round r+1 into the other buffer
      const int rn = r + 1;
      const int ttn = rn >> 2, rhn = rn & 3, pn = rn & 1;
      const unsigned char* Yblk = Y + (size_t)((gj * 4 + ttn) * 256) * D_DIM;
      const int kofs = rhn * 64;
#pragma unroll
      for (int it = 0; it < 2; ++it) {
        const size_t go = (size_t)srow[it] * D_DIM + kofs + scg[it] * 16;
        gl_lds16(Xblk + go, &Xs[pn][sc0[it] * 16]);
        gl_lds16(Yblk + go, &Ys[pn][sc0[it] * 16]);
      }
    }

    // compute round r from buffer p: 1 b128 per fragment = 2 k-steps
    lx2 af[8], bfr[4];
#pragma unroll
    for (int mt = 0; mt < 8; ++mt) {
      int row = wm * 128 + mt * 16 + l15;
      int pp  = quad ^ ((row >> 1) & 3);
      af[mt] = *(const lx2*)(&Xs[p][row * 64 + pp * 16]);
    }
#pragma unroll
    for (int nt = 0; nt < 4; ++nt) {
      int row = wn * 64 + nt * 16 + l15;
      int pp  = quad ^ ((row >> 1) & 3);
      bfr[nt] = *(const lx2*)(&Ys[p][row * 64 + pp * 16]);
    }
#pragma unroll
    for (int sub = 0; sub < 2; ++sub)
#pragma unroll
      for (int mt = 0; mt < 8; ++mt)
#pragma unroll
        for (int nt = 0; nt < 4; ++nt)
          acc[mt][nt] = __builtin_amdgcn_mfma_f32_16x16x32_fp8_fp8(
              af[mt][sub], bfr[nt][sub], acc[mt][nt], 0, 0, 0);

    if (rh == 3) {
      // tile tt done: epilogue (exp + full row-sum; diag on block-diagonal tile)
      const int bj = gj * 4 + tt;
      const int gi_base = bi * 256 + wm * 128;
#pragma unroll
      for (int mt = 0; mt < 8; ++mt) {
#pragma unroll
        for (int rr = 0; rr < 4; ++rr) {
          float part = 0.f;
#pragma unroll
          for (int nt = 0; nt < 4; ++nt)
            part += __builtin_amdgcn_exp2f(acc[mt][nt][rr] * kScaleAcc);
          part += __shfl_xor(part, 1);
          part += __shfl_xor(part, 2);
          part += __shfl_xor(part, 4);
          part += __shfl_xor(part, 8);
          if (l15 == 0) atomicAdd(&rowsum[gi_base + mt * 16 + quad * 4 + rr], part);
        }
      }
      if (bi == bj && (wn >> 1) == wm) {
        // wave's 64-col band lies in its own 128-row band: cols wn*64+nt*16+l15
        // match rows wm*128 + mtd*16 + l15 with mtd = (wn&1)*4 + nt.
#pragma unroll
        for (int nt = 0; nt < 4; ++nt) {
          const int mtd = (wn & 1) * 4 + nt;
#pragma unroll
          for (int rr = 0; rr < 4; ++rr) {
            if (l15 == quad * 4 + rr)
              diag[gi_base + mtd * 16 + l15] = acc[mtd][nt][rr];  // scaled 4096
          }
        }
      }
#pragma unroll
      for (int a = 0; a < 8; ++a)
#pragma unroll
        for (int c = 0; c < 4; ++c) acc[a][c] = (f32x4){0.f, 0.f, 0.f, 0.f};
    }
  }
  // no fence: kernel boundary provides release to finalize
}

// ------- finalize: loss = mean(log(rowsum_i - e^{d_i/T}) - d_i/T), d scaled ----
__global__ __launch_bounds__(128)
void finalize_kernel(const float* __restrict__ rowsum,
                     const float* __restrict__ diag, float* __restrict__ out) {
  const int i = blockIdx.x * 128 + threadIdx.x;   // 64 blocks x 128 = 8192
  const float d  = diag[i];                        // = 4096 * <x_i,y_i>
  const float ed = __builtin_amdgcn_exp2f(d * kScaleAcc);
  float v = __logf(rowsum[i] - ed) - d * kInvTAcc;
  v += __shfl_xor(v, 1);
  v += __shfl_xor(v, 2);
  v += __shfl_xor(v, 4);
  v += __shfl_xor(v, 8);
  v += __shfl_xor(v, 16);
  v += __shfl_xor(v, 32);
  if ((threadIdx.x & 63) == 0)
    atomicAdd(out, v * (1.0f / (float)N_ROWS));
}

extern "C" void kernel_launch(void* const* d_in, const int* in_sizes, int n_in,
                              void* d_out, int out_size, void* d_ws, size_t ws_size,
                              hipStream_t stream) {
  const float* x = (const float*)d_in[0];
  const float* y = (const float*)d_in[1];
  float* out = (float*)d_out;

  // ws layout: rowsum[N] f32 | diag[N] f32 | pad | xq[N*D] fp8 | yq[N*D] fp8
  float* rowsum = (float*)d_ws;
  float* diag   = rowsum + N_ROWS;
  unsigned char* xq = (unsigned char*)d_ws + 2 * N_ROWS * sizeof(float) + 16;
  unsigned char* yq = xq + (size_t)N_ROWS * D_DIM;

  int cvt_blocks = 2 * N_ROWS * D_DIM / 8 / 256;  // 2048
  cvt_fp8_kernel<<<cvt_blocks, 256, 0, stream>>>(x, y, xq, yq, rowsum, out);

  infonce_gemm<<<256, 512, 0, stream>>>(xq, yq, rowsum, diag);

  finalize_kernel<<<N_ROWS / 128, 128, 0, stream>>>(rowsum, diag, out);
}

// Round 11
// 121.113 us; speedup vs baseline: 2.4651x; 2.4651x over previous
//
#include <hip/hip_runtime.h>
#include <hip/hip_bf16.h>

#define N_ROWS 8192
#define D_DIM  256

// loss_i = log(sum_{j != i} exp(<x_i,y_j>/T)) - <x_i,y_i>/T ; out = mean_i loss_i
// fp8 e4m3 inputs (scale 64); acc = 4096*<x,y>; 1/4096 folded into constants.
// K-dim stored PERMUTED for 64B staging rounds: element k=(2*rh+u)*32+q*8+j is
// stored at k' = rh*64 + q*16 + u*8 + j  (rh=round 0..3, q=quad, u=k-step par).
// -> per lane per round the A/B fragment is 16 contiguous bytes (1 ds_read_b128
//    covering 2 k-steps). Dots are invariant to a shared k-permutation.
static constexpr float kQuantScale = 64.0f;
static constexpr float kScaleAcc = 20.609929155556627f / 4096.0f;  // (1/T)*log2(e)/4096
static constexpr float kInvTAcc  = 14.285714285714286f / 4096.0f;  // (1/T)/4096

typedef float f32x4 __attribute__((ext_vector_type(4)));
typedef long  lx2   __attribute__((ext_vector_type(2)));

// async 16B global->LDS: LDS dest = wave-uniform base + lane*16
__device__ __forceinline__ void gl_lds16(const void* g, void* l) {
  __builtin_amdgcn_global_load_lds(
      (const __attribute__((address_space(1))) void*)g,
      (__attribute__((address_space(3))) void*)l, 16, 0, 0);
}

// ---------------- fp32 -> fp8 e4m3 pre-convert (k-permuted) + ws/out init ------
__global__ __launch_bounds__(256)
void cvt_fp8_kernel(const float* __restrict__ x, const float* __restrict__ y,
                    unsigned char* __restrict__ xq, unsigned char* __restrict__ yq,
                    float* __restrict__ rowsum, float* __restrict__ out) {
  if (blockIdx.x == 0) {
    for (int i = threadIdx.x; i < N_ROWS; i += 256) rowsum[i] = 0.f;
    if (threadIdx.x == 0) out[0] = 0.f;
  }
  const int per_mat = N_ROWS * D_DIM / 8;  // 8 elements per thread
  int idx = blockIdx.x * blockDim.x + threadIdx.x;
  const float* src = x;
  unsigned char* dst = xq;
  int i = idx;
  if (idx >= per_mat) { src = y; dst = yq; i = idx - per_mat; }
  float4 a = ((const float4*)src)[2 * (size_t)i];
  float4 b = ((const float4*)src)[2 * (size_t)i + 1];
  int v0 = 0, v1 = 0;
  v0 = __builtin_amdgcn_cvt_pk_fp8_f32(a.x * kQuantScale, a.y * kQuantScale, v0, false);
  v0 = __builtin_amdgcn_cvt_pk_fp8_f32(a.z * kQuantScale, a.w * kQuantScale, v0, true);
  v1 = __builtin_amdgcn_cvt_pk_fp8_f32(b.x * kQuantScale, b.y * kQuantScale, v1, false);
  v1 = __builtin_amdgcn_cvt_pk_fp8_f32(b.z * kQuantScale, b.w * kQuantScale, v1, true);
  // elements k = c*8..c*8+7, c = (k-step ug)*4 + q; store at rh*64 + q*16 + u*8
  const int row = i >> 5;
  const int c   = i & 31;
  const int ug  = c >> 2;         // k-step 0..7
  const int q   = c & 3;          // quad
  const int rh  = ug >> 1;        // staging round 0..3
  const int u   = ug & 1;         // k-step parity within round
  const size_t off = (size_t)row * D_DIM + rh * 64 + q * 16 + u * 8;
  *(int2*)(dst + off) = make_int2(v0, v1);
}

// ---------------- persistent fused GEMM(fp8) + exp + row-sum -------------------
// 256 persistent blocks (1/CU), 512 threads = 8 waves (2x4). Each block owns
// X-row-block bi = b>>3 (256 rows) and computes 4 tiles bj = (b&7)*4 + tt of
// 256x256. Flat loop over 16 rounds (4 tiles x 4 K-quarters of 64B), LDS
// double-buffered (2 x 32 KB = 64 KB). Wave tile 128x64 = 8x4 MFMA tiles.
// ALL acc[] indices must be compile-time constants (R10 lesson: one runtime
// index -> whole 128-reg acc array demoted to scratch -> 1.4 GB spill traffic).
// No device-scope fences (R4 lesson: they nuke per-XCD L2).
__global__ __launch_bounds__(512, 2)
void infonce_gemm(const unsigned char* __restrict__ X,
                  const unsigned char* __restrict__ Y,
                  float* __restrict__ rowsum, float* __restrict__ diag) {
  __shared__ unsigned char Xs[2][256 * 64];   // 2 x 16 KB
  __shared__ unsigned char Ys[2][256 * 64];   // 2 x 16 KB

  const int b  = blockIdx.x;        // 0..255
  const int bi = b >> 3;            // 0..31, fixed X-row-block (256 rows)
  const int gj = b & 7;             // col-group: bj = gj*4 + tt, tt=0..3

  const int t    = threadIdx.x;
  const int lane = t & 63;
  const int wave = t >> 6;        // 0..7
  const int wm   = wave >> 2;     // 0..1  (128-row half)
  const int wn   = wave & 3;      // 0..3  (64-col quarter)
  const int quad = lane >> 4;     // 0..3
  const int l15  = lane & 15;

  const unsigned char* Xblk = X + (size_t)(bi * 256) * D_DIM;

  // staging geometry: 1024 slots(16B) per matrix per round; it in {0,1}
  int sc0[2], srow[2], scg[2];
#pragma unroll
  for (int it = 0; it < 2; ++it) {
    const int c0 = (it * 8 + wave) * 64;   // wave-uniform slot base
    const int s  = c0 + lane;
    const int row = s >> 2;                // 0..255
    sc0[it]  = c0;
    srow[it] = row;
    scg[it]  = (s & 3) ^ ((row >> 1) & 3); // global chunk for this LDS slot
  }

  f32x4 acc[8][4];
#pragma unroll
  for (int a = 0; a < 8; ++a)
#pragma unroll
    for (int c = 0; c < 4; ++c) acc[a][c] = (f32x4){0.f, 0.f, 0.f, 0.f};

  // prologue: stage round 0 (tile 0, quarter 0) into buffer 0
  {
    const unsigned char* Yblk = Y + (size_t)((gj * 4) * 256) * D_DIM;
#pragma unroll
    for (int it = 0; it < 2; ++it) {
      const size_t go = (size_t)srow[it] * D_DIM + scg[it] * 16;
      gl_lds16(Xblk + go, &Xs[0][sc0[it] * 16]);
      gl_lds16(Yblk + go, &Ys[0][sc0[it] * 16]);
    }
  }

#pragma unroll 4
  for (int r = 0; r < 16; ++r) {
    const int tt = r >> 2;        // tile 0..3
    const int rh = r & 3;         // K-quarter
    const int p  = r & 1;         // LDS buffer parity

    __syncthreads();   // staging of round r drained (vmcnt(0) before barrier)

    if (r < 15) {      // stage round r+1 into the other buffer
      const int rn = r + 1;
      const int ttn = rn >> 2, rhn = rn & 3, pn = rn & 1;
      const unsigned char* Yblk = Y + (size_t)((gj * 4 + ttn) * 256) * D_DIM;
      const int kofs = rhn * 64;
#pragma unroll
      for (int it = 0; it < 2; ++it) {
        const size_t go = (size_t)srow[it] * D_DIM + kofs + scg[it] * 16;
        gl_lds16(Xblk + go, &Xs[pn][sc0[it] * 16]);
        gl_lds16(Yblk + go, &Ys[pn][sc0[it] * 16]);
      }
    }

    // compute round r from buffer p: 1 b128 per fragment = 2 k-steps
    lx2 af[8], bfr[4];
#pragma unroll
    for (int mt = 0; mt < 8; ++mt) {
      int row = wm * 128 + mt * 16 + l15;
      int pp  = quad ^ ((row >> 1) & 3);
      af[mt] = *(const lx2*)(&Xs[p][row * 64 + pp * 16]);
    }
#pragma unroll
    for (int nt = 0; nt < 4; ++nt) {
      int row = wn * 64 + nt * 16 + l15;
      int pp  = quad ^ ((row >> 1) & 3);
      bfr[nt] = *(const lx2*)(&Ys[p][row * 64 + pp * 16]);
    }
#pragma unroll
    for (int sub = 0; sub < 2; ++sub)
#pragma unroll
      for (int mt = 0; mt < 8; ++mt)
#pragma unroll
        for (int nt = 0; nt < 4; ++nt)
          acc[mt][nt] = __builtin_amdgcn_mfma_f32_16x16x32_fp8_fp8(
              af[mt][sub], bfr[nt][sub], acc[mt][nt], 0, 0, 0);

    if (rh == 3) {
      // tile tt done: epilogue (exp + full row-sum; diag on block-diagonal tile)
      const int bj = gj * 4 + tt;
      const int gi_base = bi * 256 + wm * 128;
#pragma unroll
      for (int mt = 0; mt < 8; ++mt) {
#pragma unroll
        for (int rr = 0; rr < 4; ++rr) {
          float part = 0.f;
#pragma unroll
          for (int nt = 0; nt < 4; ++nt)
            part += __builtin_amdgcn_exp2f(acc[mt][nt][rr] * kScaleAcc);
          part += __shfl_xor(part, 1);
          part += __shfl_xor(part, 2);
          part += __shfl_xor(part, 4);
          part += __shfl_xor(part, 8);
          if (l15 == 0) atomicAdd(&rowsum[gi_base + mt * 16 + quad * 4 + rr], part);
        }
      }
      if (bi == bj && (wn >> 1) == wm) {
        // wave's 64-col band lies in its own 128-row band. Diagonal element of
        // col-tile nt is row-tile mtd = (wn&1)*4 + nt — branch on (wn&1) so
        // every acc[] index is COMPILE-TIME (R10 scratch-demotion lesson).
        if ((wn & 1) == 0) {
#pragma unroll
          for (int nt = 0; nt < 4; ++nt)
#pragma unroll
            for (int rr = 0; rr < 4; ++rr)
              if (l15 == quad * 4 + rr)
                diag[gi_base + nt * 16 + l15] = acc[nt][nt][rr];        // scaled 4096
        } else {
#pragma unroll
          for (int nt = 0; nt < 4; ++nt)
#pragma unroll
            for (int rr = 0; rr < 4; ++rr)
              if (l15 == quad * 4 + rr)
                diag[gi_base + (4 + nt) * 16 + l15] = acc[4 + nt][nt][rr];
        }
      }
#pragma unroll
      for (int a = 0; a < 8; ++a)
#pragma unroll
        for (int c = 0; c < 4; ++c) acc[a][c] = (f32x4){0.f, 0.f, 0.f, 0.f};
    }
  }
  // no fence: kernel boundary provides release to finalize
}

// ------- finalize: loss = mean(log(rowsum_i - e^{d_i/T}) - d_i/T), d scaled ----
__global__ __launch_bounds__(128)
void finalize_kernel(const float* __restrict__ rowsum,
                     const float* __restrict__ diag, float* __restrict__ out) {
  const int i = blockIdx.x * 128 + threadIdx.x;   // 64 blocks x 128 = 8192
  const float d  = diag[i];                        // = 4096 * <x_i,y_i>
  const float ed = __builtin_amdgcn_exp2f(d * kScaleAcc);
  float v = __logf(rowsum[i] - ed) - d * kInvTAcc;
  v += __shfl_xor(v, 1);
  v += __shfl_xor(v, 2);
  v += __shfl_xor(v, 4);
  v += __shfl_xor(v, 8);
  v += __shfl_xor(v, 16);
  v += __shfl_xor(v, 32);
  if ((threadIdx.x & 63) == 0)
    atomicAdd(out, v * (1.0f / (float)N_ROWS));
}

extern "C" void kernel_launch(void* const* d_in, const int* in_sizes, int n_in,
                              void* d_out, int out_size, void* d_ws, size_t ws_size,
                              hipStream_t stream) {
  const float* x = (const float*)d_in[0];
  const float* y = (const float*)d_in[1];
  float* out = (float*)d_out;

  // ws layout: rowsum[N] f32 | diag[N] f32 | pad | xq[N*D] fp8 | yq[N*D] fp8
  float* rowsum = (float*)d_ws;
  float* diag   = rowsum + N_ROWS;
  unsigned char* xq = (unsigned char*)d_ws + 2 * N_ROWS * sizeof(float) + 16;
  unsigned char* yq = xq + (size_t)N_ROWS * D_DIM;

  int cvt_blocks = 2 * N_ROWS * D_DIM / 8 / 256;  // 2048
  cvt_fp8_kernel<<<cvt_blocks, 256, 0, stream>>>(x, y, xq, yq, rowsum, out);

  infonce_gemm<<<256, 512, 0, stream>>>(xq, yq, rowsum, diag);

  finalize_kernel<<<N_ROWS / 128, 128, 0, stream>>>(rowsum, diag, out);
}

// Round 12
// 118.841 us; speedup vs baseline: 2.5123x; 1.0191x over previous
//
#include <hip/hip_runtime.h>
#include <hip/hip_bf16.h>

#define N_ROWS 8192
#define D_DIM  256

// loss_i = log(sum_{j != i} exp(<x_i,y_j>/T)) - <x_i,y_i>/T ; out = mean_i loss_i
// fp8 e4m3 inputs (scale 64); acc = 4096*<x,y>; 1/4096 folded into constants.
// K-dim stored PERMUTED: element k (ks=k>>5, q=(k>>3)&3, u=ks&1, rh=ks>>1,
// j=k&7) stored at k' = rh*64 + q*16 + u*8 + j. A lane (quad q) then reads
// k-step pair (2g,2g+1) as ONE contiguous b128 at chunk g*4+q. Dot products
// are invariant to a shared k-permutation.
static constexpr float kQuantScale = 64.0f;
static constexpr float kScaleAcc = 20.609929155556627f / 4096.0f;  // (1/T)*log2(e)/4096
static constexpr float kInvTAcc  = 14.285714285714286f / 4096.0f;  // (1/T)/4096

typedef float f32x4 __attribute__((ext_vector_type(4)));
typedef long  lx2   __attribute__((ext_vector_type(2)));

// async 16B global->LDS: LDS dest = wave-uniform base + lane*16
__device__ __forceinline__ void gl_lds16(const void* g, void* l) {
  __builtin_amdgcn_global_load_lds(
      (const __attribute__((address_space(1))) void*)g,
      (__attribute__((address_space(3))) void*)l, 16, 0, 0);
}

// ---------------- fp32 -> fp8 e4m3 pre-convert (k-permuted) + ws init ----------
__global__ __launch_bounds__(256)
void cvt_fp8_kernel(const float* __restrict__ x, const float* __restrict__ y,
                    unsigned char* __restrict__ xq, unsigned char* __restrict__ yq,
                    float* __restrict__ rowsum, unsigned int* __restrict__ done) {
  if (blockIdx.x == 0) {
    for (int i = threadIdx.x; i < N_ROWS; i += 256) rowsum[i] = 0.f;
    if (threadIdx.x == 0) *done = 0u;
  }
  const int per_mat = N_ROWS * D_DIM / 8;  // 8 elements per thread
  int idx = blockIdx.x * blockDim.x + threadIdx.x;
  const float* src = x;
  unsigned char* dst = xq;
  int i = idx;
  if (idx >= per_mat) { src = y; dst = yq; i = idx - per_mat; }
  float4 a = ((const float4*)src)[2 * (size_t)i];
  float4 b = ((const float4*)src)[2 * (size_t)i + 1];
  int v0 = 0, v1 = 0;
  v0 = __builtin_amdgcn_cvt_pk_fp8_f32(a.x * kQuantScale, a.y * kQuantScale, v0, false);
  v0 = __builtin_amdgcn_cvt_pk_fp8_f32(a.z * kQuantScale, a.w * kQuantScale, v0, true);
  v1 = __builtin_amdgcn_cvt_pk_fp8_f32(b.x * kQuantScale, b.y * kQuantScale, v1, false);
  v1 = __builtin_amdgcn_cvt_pk_fp8_f32(b.z * kQuantScale, b.w * kQuantScale, v1, true);
  // elements k = c*8..c*8+7, c = ks*4 + q; store at (ks>>1)*64 + q*16 + (ks&1)*8
  const int row = i >> 5;
  const int c   = i & 31;
  const int ks  = c >> 2;
  const int q   = c & 3;
  const size_t off = (size_t)row * D_DIM + (ks >> 1) * 64 + q * 16 + (ks & 1) * 8;
  *(int2*)(dst + off) = make_int2(v0, v1);
}

// ---------------- persistent fused GEMM(fp8) + exp + row-sum + finalize --------
// 256 persistent blocks (1/CU), 512 threads = 8 waves (wm=wave>>1 in 0..3,
// wn=wave&1). X-block: 256 rows x full K staged ONCE into 64 KB LDS. Y: 8
// tiles of 128 cols x full K (32 KB each), double-buffered (64 KB). 8 fat
// rounds, ONE barrier per tile; Y staging hides under ~5k cy of MFMA.
// Wave tile 64x64 = 4x4 MFMA tiles (acc 64 VGPRs; all indices compile-time —
// R10 lesson). LDS swizzle: chunk pos = chunk ^ (row&15) -> staging stays
// 128B-line coalesced and fragment b128 reads are ≤2-way (free).
// Producers need NO fence (rowsum/diag are device-scope atomics; the barrier
// before the ticket drains vmcnt). Only the single last block fences once.
__global__ __launch_bounds__(512, 1)
void infonce_gemm(const unsigned char* __restrict__ X,
                  const unsigned char* __restrict__ Y,
                  float* __restrict__ rowsum, float* __restrict__ diag,
                  unsigned int* __restrict__ done, float* __restrict__ out) {
  __shared__ unsigned char Xs[256 * 256];      // 64 KB, X-block full-K
  __shared__ unsigned char Ys[2][128 * 256];   // 2 x 32 KB, Y tile dbuf
  __shared__ unsigned int ticket_s;

  const int b  = blockIdx.x;        // 0..255
  const int bi = b >> 3;            // 0..31: X-row-block (256 rows)
  const int gj = b & 7;             // col-group: col-tile ct = gj*8 + tt

  const int t    = threadIdx.x;
  const int lane = t & 63;
  const int wave = t >> 6;        // 0..7
  const int wm   = wave >> 1;     // 0..3  (64-row band)
  const int wn   = wave & 1;      // 0..1  (64-col half)
  const int quad = lane >> 4;     // 0..3
  const int l15  = lane & 15;

  const unsigned char* Xblk = X + (size_t)(bi * 256) * D_DIM;

  // ---- prologue: stage X (4096 slots of 16B, 8 per thread) ----
#pragma unroll
  for (int it = 0; it < 8; ++it) {
    const int c0  = (it * 8 + wave) * 64;
    const int s   = c0 + lane;
    const int row = s >> 4;                 // 0..255
    const int cg  = (s & 15) ^ (row & 15);  // inverse swizzle on global side
    gl_lds16(Xblk + (size_t)row * D_DIM + cg * 16, &Xs[c0 * 16]);
  }
  // stage Y tile 0 (2048 slots, 4 per thread) into buffer 0
  {
    const unsigned char* Yblk = Y + (size_t)(gj * 8) * 128 * D_DIM;
#pragma unroll
    for (int it = 0; it < 4; ++it) {
      const int c0  = (it * 8 + wave) * 64;
      const int s   = c0 + lane;
      const int row = s >> 4;                 // 0..127
      const int cg  = (s & 15) ^ (row & 15);
      gl_lds16(Yblk + (size_t)row * D_DIM + cg * 16, &Ys[0][c0 * 16]);
    }
  }

  f32x4 acc[4][4];
#pragma unroll
  for (int a = 0; a < 4; ++a)
#pragma unroll
    for (int c = 0; c < 4; ++c) acc[a][c] = (f32x4){0.f, 0.f, 0.f, 0.f};

  for (int tt = 0; tt < 8; ++tt) {
    const int p = tt & 1;

    __syncthreads();   // round tt staged (barrier drains vmcnt)

    if (tt < 7) {      // stage Y tile tt+1 into the other buffer
      const unsigned char* Yblk = Y + (size_t)(gj * 8 + tt + 1) * 128 * D_DIM;
#pragma unroll
      for (int it = 0; it < 4; ++it) {
        const int c0  = (it * 8 + wave) * 64;
        const int s   = c0 + lane;
        const int row = s >> 4;
        const int cg  = (s & 15) ^ (row & 15);
        gl_lds16(Yblk + (size_t)row * D_DIM + cg * 16, &Ys[p ^ 1][c0 * 16]);
      }
    }

    // full-K compute: 4 groups of 2 k-steps; 1 b128 per fragment per group
#pragma unroll
    for (int g = 0; g < 4; ++g) {
      lx2 af[4], bfr[4];
#pragma unroll
      for (int mt = 0; mt < 4; ++mt) {
        const int row = wm * 64 + mt * 16 + l15;
        const int pos = (g * 4 + quad) ^ l15;       // row&15 == l15
        af[mt] = *(const lx2*)(&Xs[row * 256 + pos * 16]);
      }
#pragma unroll
      for (int nt = 0; nt < 4; ++nt) {
        const int row = wn * 64 + nt * 16 + l15;
        const int pos = (g * 4 + quad) ^ l15;
        bfr[nt] = *(const lx2*)(&Ys[p][row * 256 + pos * 16]);
      }
#pragma unroll
      for (int sub = 0; sub < 2; ++sub)
#pragma unroll
        for (int mt = 0; mt < 4; ++mt)
#pragma unroll
          for (int nt = 0; nt < 4; ++nt)
            acc[mt][nt] = __builtin_amdgcn_mfma_f32_16x16x32_fp8_fp8(
                af[mt][sub], bfr[nt][sub], acc[mt][nt], 0, 0, 0);
    }

    // ---- tile epilogue: exp + FULL row-sum (diag removed in finalize) ----
    const int gi_base = bi * 256 + wm * 64;
#pragma unroll
    for (int mt = 0; mt < 4; ++mt) {
#pragma unroll
      for (int rr = 0; rr < 4; ++rr) {
        float part = 0.f;
#pragma unroll
        for (int nt = 0; nt < 4; ++nt)
          part += __builtin_amdgcn_exp2f(acc[mt][nt][rr] * kScaleAcc);
        part += __shfl_xor(part, 1);
        part += __shfl_xor(part, 2);
        part += __shfl_xor(part, 4);
        part += __shfl_xor(part, 8);
        if (l15 == 0) atomicAdd(&rowsum[gi_base + mt * 16 + quad * 4 + rr], part);
      }
    }
    // diagonal: col-tile ct = gj*8+tt overlaps rows iff ct==2*bi (+0) or
    // 2*bi+1 (+128). In-wave: mt==nt and wm==wn (+0) / wm==wn+2 (+128).
    // atomicExch (device-scope) so the last block can read it coherently.
    {
      const int ct = gj * 8 + tt;
      const bool d0 = (ct == 2 * bi)     && (wm == wn);
      const bool d1 = (ct == 2 * bi + 1) && (wm == wn + 2);
      if (d0 || d1) {
#pragma unroll
        for (int nt = 0; nt < 4; ++nt)
#pragma unroll
          for (int rr = 0; rr < 4; ++rr)
            if (l15 == quad * 4 + rr)
              atomicExch(&diag[gi_base + nt * 16 + l15], acc[nt][nt][rr]);
      }
    }
#pragma unroll
    for (int a = 0; a < 4; ++a)
#pragma unroll
      for (int c = 0; c < 4; ++c) acc[a][c] = (f32x4){0.f, 0.f, 0.f, 0.f};
  }

  // ---- last-block finalize (single fence — not per-block, R4 lesson) ----
  __syncthreads();                       // drains this block's atomics (vmcnt)
  if (t == 0) ticket_s = atomicAdd(done, 1u);
  __syncthreads();
  if (ticket_s == 255u) {
    __threadfence();                     // one acquire, one block only
    float local = 0.f;
    for (int i = t; i < N_ROWS; i += 512) {
      const float rs = atomicAdd(&rowsum[i], 0.0f);   // device-coherent read
      const float d  = atomicAdd(&diag[i], 0.0f);
      local += __logf(rs - __builtin_amdgcn_exp2f(d * kScaleAcc)) - d * kInvTAcc;
    }
    float* red = (float*)Xs;
    red[t] = local;
    __syncthreads();
    for (int s2 = 256; s2 > 0; s2 >>= 1) {
      if (t < s2) red[t] += red[t + s2];
      __syncthreads();
    }
    if (t == 0) out[0] = red[0] / (float)N_ROWS;
  }
}

extern "C" void kernel_launch(void* const* d_in, const int* in_sizes, int n_in,
                              void* d_out, int out_size, void* d_ws, size_t ws_size,
                              hipStream_t stream) {
  const float* x = (const float*)d_in[0];
  const float* y = (const float*)d_in[1];
  float* out = (float*)d_out;

  // ws layout: rowsum[N] f32 | diag[N] f32 | done u32(+pad) | xq | yq
  float* rowsum = (float*)d_ws;
  float* diag   = rowsum + N_ROWS;
  unsigned int* done = (unsigned int*)(diag + N_ROWS);
  unsigned char* xq = (unsigned char*)d_ws + 2 * N_ROWS * sizeof(float) + 16;
  unsigned char* yq = xq + (size_t)N_ROWS * D_DIM;

  int cvt_blocks = 2 * N_ROWS * D_DIM / 8 / 256;  // 2048
  cvt_fp8_kernel<<<cvt_blocks, 256, 0, stream>>>(x, y, xq, yq, rowsum, done);

  infonce_gemm<<<256, 512, 0, stream>>>(xq, yq, rowsum, diag, done, out);
}